// Round 11
// baseline (59.196 us; speedup 1.0000x reference)
//
#include <hip/hip_runtime.h>

static constexpr int B = 8, Himg = 512, Wimg = 512, TH = 512, TW = 512;
static constexpr int NPIX = B * Himg * Wimg;          // 2,097,152
static constexpr int BPB = 32;                        // minmax blocks per batch
static constexpr int WBLOCKS = NPIX / 256;            // 8192  (weights role)
static constexpr int CBLOCKS = 2 * NPIX / 256;        // 16384 (coords role)

typedef float f4 __attribute__((ext_vector_type(4)));

// ---------------- kernel 1: per-block min/max partials (no atomics) --------
__global__ __launch_bounds__(256) void minmax_kernel(const float* __restrict__ cm,
                                                     float* __restrict__ wsmin,
                                                     float* __restrict__ wsmax) {
    int b   = blockIdx.x / BPB;
    int blk = blockIdx.x % BPB;
    const f4* p = (const f4*)(cm + (size_t)b * Himg * Wimg);
    float mn = 3.4e38f, mx = -3.4e38f;
    int base = blk * 2048;
    #pragma unroll
    for (int k = 0; k < 8; ++k) {
        f4 v = p[base + k * 256 + threadIdx.x];
        mn = fminf(mn, fminf(fminf(v.x, v.y), fminf(v.z, v.w)));
        mx = fmaxf(mx, fmaxf(fmaxf(v.x, v.y), fmaxf(v.z, v.w)));
    }
    #pragma unroll
    for (int off = 32; off; off >>= 1) {
        mn = fminf(mn, __shfl_xor(mn, off));
        mx = fmaxf(mx, __shfl_xor(mx, off));
    }
    __shared__ float smn[4], smx[4];
    int wave = threadIdx.x >> 6, lane = threadIdx.x & 63;
    if (lane == 0) { smn[wave] = mn; smx[wave] = mx; }
    __syncthreads();
    if (threadIdx.x == 0) {
        mn = fminf(fminf(smn[0], smn[1]), fminf(smn[2], smn[3]));
        mx = fmaxf(fmaxf(smx[0], smx[1]), fmaxf(smx[2], smx[3]));
        wsmin[b * BPB + blk] = mn;
        wsmax[b * BPB + blk] = mx;
    }
}

// ---------------- kernel 2: density (f32 conv + borderline f64 fixup) ------
// |D_f32 - D_f64| <= ~3e-6 (25-term f32 FMA on [0,1] data); pixels with
// |D32 - thr| >= 1e-4 decide identically to the f64/numpy reference; rare
// borderline pixels recomputed exactly (f64 25-tap from global). Decision
// (num = 1<<code) encoded in the 2 low mantissa bits of the stored density.
__global__ __launch_bounds__(256) void density_kernel(const float* __restrict__ cm,
                                                      const float* __restrict__ kern,
                                                      const float* __restrict__ wsmin,
                                                      const float* __restrict__ wsmax,
                                                      float* __restrict__ dens) {
    __shared__ float tile[36][37];      // normalized halo, f32 (padded stride)
    __shared__ float kf[25];

    int tid = threadIdx.x;
    int b = blockIdx.z;
    int bx = blockIdx.x * 32, by = blockIdx.y * 32;

    if (tid < 25) kf[tid] = kern[tid];

    float mnf = 3.4e38f, mxf = -3.4e38f;
    #pragma unroll
    for (int k = 0; k < BPB; ++k) {
        mnf = fminf(mnf, wsmin[b * BPB + k]);
        mxf = fmaxf(mxf, wsmax[b * BPB + k]);
    }
    bool ok = mxf > mnf;
    double mn = (double)mnf;
    double inv = ok ? (1.0 / ((double)mxf - mn)) : 0.0;
    float mnf32 = mnf;
    float invf32 = (float)inv;

    const float* img = cm + (size_t)b * Himg * Wimg;
    for (int idx = tid; idx < 36 * 36; idx += 256) {
        int r = idx / 36, c = idx % 36;
        int gy = by + r - 2, gx = bx + c - 2;
        float v = 0.0f;
        if (gy >= 0 && gy < Himg && gx >= 0 && gx < Wimg)
            v = ok ? (img[gy * Wimg + gx] - mnf32) * invf32 : 0.0f;
        tile[r][c] = v;
    }
    __syncthreads();

    int ox = tid & 31;
    int oy0 = (tid >> 5) << 2;                    // 0,4,...,28
    float acc[4] = {0.f, 0.f, 0.f, 0.f};
    #pragma unroll
    for (int yy = 0; yy < 8; ++yy) {
        float rv[5];
        #pragma unroll
        for (int dx = 0; dx < 5; ++dx) rv[dx] = tile[oy0 + yy][ox + dx];
        #pragma unroll
        for (int r = 0; r < 4; ++r) {
            int dy = yy - r;
            if (dy >= 0 && dy < 5) {
                #pragma unroll
                for (int dx = 0; dx < 5; ++dx)
                    acc[r] = fmaf(rv[dx], kf[dy * 5 + dx], acc[r]);
            }
        }
    }
    #pragma unroll
    for (int r = 0; r < 4; ++r) {
        int oy = oy0 + r;
        float D32 = 0.1f + 0.9f * sqrtf(fmaxf(acc[r], 0.0f));
        float Dout = D32;
        int code;
        if (fabsf(D32 - 0.7f) < 1e-4f || fabsf(D32 - 0.4f) < 1e-4f) {
            double s64 = 0.0;
            #pragma unroll
            for (int dy = 0; dy < 5; ++dy)
                for (int dx = 0; dx < 5; ++dx) {
                    int gy = by + oy + dy - 2, gx = bx + ox + dx - 2;
                    double v = 0.0;
                    if (gy >= 0 && gy < Himg && gx >= 0 && gx < Wimg)
                        v = ((double)img[gy * Wimg + gx] - mn) * inv;
                    s64 += v * (double)kern[dy * 5 + dx];
                }
            double D64 = 0.1 + 0.9 * sqrt(s64);
            code = D64 > 0.7 ? 2 : (D64 > 0.4 ? 1 : 0);
            Dout = (float)D64;
        } else {
            code = D32 > 0.7f ? 2 : (D32 > 0.4f ? 1 : 0);
        }
        unsigned u = (__float_as_uint(Dout) & ~3u) | (unsigned)code;
        dens[(size_t)b * Himg * Wimg + (size_t)(by + oy) * Wimg + (bx + ox)] =
            __uint_as_float(u);
    }
}

// ---------------- kernel 3: dual-role copy-shaped streamer -----------------
// W-role (blocks [0, WBLOCKS)):    thread = pixel:      dens 4B -> weights f4.
// C-role (blocks [WBLOCKS, end)):  thread = half-pixel: rnd f4 + dens -> coords f4.
// No LDS, no barriers, block-uniform branch, every access lane-contiguous,
// one-shot blocks freely interleaved by the dispatcher.
__global__ __launch_bounds__(256) void stream_kernel(const float* __restrict__ rnd,
                                                     const float* __restrict__ dens,
                                                     float* __restrict__ coords,
                                                     float* __restrict__ weights) {
    int bid = blockIdx.x;
    if (bid < WBLOCKS) {
        int p = bid * 256 + threadIdx.x;            // pixel id
        float local = dens[p];
        int code = __float_as_uint(local) & 3;
        int num = 1 << code;
        // local / num, num in {1,2,4}: exact pow2 scale
        float invw = local * __uint_as_float(0x3f800000u - ((unsigned)code << 23));
        f4 w;
        w.x = invw;
        w.y = (num > 1) ? invw : 0.0f;
        w.z = (num > 3) ? invw : 0.0f;
        w.w = w.z;
        ((f4*)weights)[p] = w;
    } else {
        int t = (bid - WBLOCKS) * 256 + threadIdx.x; // half-pixel id
        int p = t >> 1;
        float local = dens[p];                       // 2-lane shared, coalesced
        bool useoff = (__float_as_uint(local) & 3) != 0;

        int rem = p & (Himg * Wimg - 1);
        float yb = -1.0f + (rem >> 9) * (2.0f / (TH - 1));
        float xb = -1.0f + (rem & 511) * (2.0f / (TW - 1));
        const float cy = (2.0f / TH) * 0.8f;
        const float cx = (2.0f / TW) * 0.8f;

        f4 r = ((const f4*)rnd)[t];
        f4 c;
        c.x = yb + (useoff ? (r.x - 0.5f) * cy : 0.0f);
        c.y = xb + (useoff ? (r.y - 0.5f) * cx : 0.0f);
        c.z = yb + (useoff ? (r.z - 0.5f) * cy : 0.0f);
        c.w = xb + (useoff ? (r.w - 0.5f) * cx : 0.0f);
        ((f4*)coords)[t] = c;
    }
}

extern "C" void kernel_launch(void* const* d_in, const int* in_sizes, int n_in,
                              void* d_out, int out_size, void* d_ws, size_t ws_size,
                              hipStream_t stream) {
    const float* cm   = (const float*)d_in[0];
    const float* rnd  = (const float*)d_in[1];
    const float* kern = (const float*)d_in[2];
    float* out     = (float*)d_out;
    float* coords  = out;                                   // 8*512*512*4*2
    float* weights = out + (size_t)B * TH * TW * 8;         // 8*512*512*4
    float* dens    = weights + (size_t)B * TH * TW * 4;     // 8*512*512
    float* wsmin   = (float*)d_ws;                          // 256 floats
    float* wsmax   = wsmin + B * BPB;                       // 256 floats

    minmax_kernel<<<B * BPB, 256, 0, stream>>>(cm, wsmin, wsmax);
    dim3 gridD(Wimg / 32, Himg / 32, B);
    density_kernel<<<gridD, 256, 0, stream>>>(cm, kern, wsmin, wsmax, dens);
    stream_kernel<<<WBLOCKS + CBLOCKS, 256, 0, stream>>>(rnd, dens, coords, weights);
}

// Round 12
// 58.178 us; speedup vs baseline: 1.0175x; 1.0175x over previous
//
#include <hip/hip_runtime.h>

static constexpr int B = 8, Himg = 512, Wimg = 512, TH = 512, TW = 512;
static constexpr int NPIX = B * Himg * Wimg;          // 2,097,152
static constexpr int BPB = 32;                        // minmax blocks per batch

typedef float f4 __attribute__((ext_vector_type(4)));
typedef float f2 __attribute__((ext_vector_type(2)));

// ---------------- kernel 1: per-block min/max partials (no atomics) --------
__global__ __launch_bounds__(256) void minmax_kernel(const float* __restrict__ cm,
                                                     float* __restrict__ wsmin,
                                                     float* __restrict__ wsmax) {
    int b   = blockIdx.x / BPB;
    int blk = blockIdx.x % BPB;
    const f4* p = (const f4*)(cm + (size_t)b * Himg * Wimg);
    float mn = 3.4e38f, mx = -3.4e38f;
    int base = blk * 2048;
    #pragma unroll
    for (int k = 0; k < 8; ++k) {
        f4 v = p[base + k * 256 + threadIdx.x];
        mn = fminf(mn, fminf(fminf(v.x, v.y), fminf(v.z, v.w)));
        mx = fmaxf(mx, fmaxf(fmaxf(v.x, v.y), fmaxf(v.z, v.w)));
    }
    #pragma unroll
    for (int off = 32; off; off >>= 1) {
        mn = fminf(mn, __shfl_xor(mn, off));
        mx = fmaxf(mx, __shfl_xor(mx, off));
    }
    __shared__ float smn[4], smx[4];
    int wave = threadIdx.x >> 6, lane = threadIdx.x & 63;
    if (lane == 0) { smn[wave] = mn; smx[wave] = mx; }
    __syncthreads();
    if (threadIdx.x == 0) {
        mn = fminf(fminf(smn[0], smn[1]), fminf(smn[2], smn[3]));
        mx = fmaxf(fmaxf(smx[0], smx[1]), fmaxf(smx[2], smx[3]));
        wsmin[b * BPB + blk] = mn;
        wsmax[b * BPB + blk] = mx;
    }
}

// ---------------- kernel 2: density (f32 conv + borderline f64 fixup) ------
// |D_f32 - D_f64| <= ~3e-6; pixels with |D32 - thr| >= 1e-4 decide identically
// to the f64/numpy reference; rare borderline pixels recomputed exactly (f64
// 25-tap from global). Decision (num = 1<<code) encoded in the 2 low mantissa
// bits of the stored density.
__global__ __launch_bounds__(256) void density_kernel(const float* __restrict__ cm,
                                                      const float* __restrict__ kern,
                                                      const float* __restrict__ wsmin,
                                                      const float* __restrict__ wsmax,
                                                      float* __restrict__ dens) {
    __shared__ float tile[36][37];      // normalized halo, f32 (padded stride)
    __shared__ float kf[25];

    int tid = threadIdx.x;
    int b = blockIdx.z;
    int bx = blockIdx.x * 32, by = blockIdx.y * 32;

    if (tid < 25) kf[tid] = kern[tid];

    float mnf = 3.4e38f, mxf = -3.4e38f;
    #pragma unroll
    for (int k = 0; k < BPB; ++k) {
        mnf = fminf(mnf, wsmin[b * BPB + k]);
        mxf = fmaxf(mxf, wsmax[b * BPB + k]);
    }
    bool ok = mxf > mnf;
    double mn = (double)mnf;
    double inv = ok ? (1.0 / ((double)mxf - mn)) : 0.0;
    float mnf32 = mnf;
    float invf32 = (float)inv;

    const float* img = cm + (size_t)b * Himg * Wimg;
    for (int idx = tid; idx < 36 * 36; idx += 256) {
        int r = idx / 36, c = idx % 36;
        int gy = by + r - 2, gx = bx + c - 2;
        float v = 0.0f;
        if (gy >= 0 && gy < Himg && gx >= 0 && gx < Wimg)
            v = ok ? (img[gy * Wimg + gx] - mnf32) * invf32 : 0.0f;
        tile[r][c] = v;
    }
    __syncthreads();

    int ox = tid & 31;
    int oy0 = (tid >> 5) << 2;                    // 0,4,...,28
    float acc[4] = {0.f, 0.f, 0.f, 0.f};
    #pragma unroll
    for (int yy = 0; yy < 8; ++yy) {
        float rv[5];
        #pragma unroll
        for (int dx = 0; dx < 5; ++dx) rv[dx] = tile[oy0 + yy][ox + dx];
        #pragma unroll
        for (int r = 0; r < 4; ++r) {
            int dy = yy - r;
            if (dy >= 0 && dy < 5) {
                #pragma unroll
                for (int dx = 0; dx < 5; ++dx)
                    acc[r] = fmaf(rv[dx], kf[dy * 5 + dx], acc[r]);
            }
        }
    }
    #pragma unroll
    for (int r = 0; r < 4; ++r) {
        int oy = oy0 + r;
        float D32 = 0.1f + 0.9f * sqrtf(fmaxf(acc[r], 0.0f));
        float Dout = D32;
        int code;
        if (fabsf(D32 - 0.7f) < 1e-4f || fabsf(D32 - 0.4f) < 1e-4f) {
            double s64 = 0.0;
            #pragma unroll
            for (int dy = 0; dy < 5; ++dy)
                for (int dx = 0; dx < 5; ++dx) {
                    int gy = by + oy + dy - 2, gx = bx + ox + dx - 2;
                    double v = 0.0;
                    if (gy >= 0 && gy < Himg && gx >= 0 && gx < Wimg)
                        v = ((double)img[gy * Wimg + gx] - mn) * inv;
                    s64 += v * (double)kern[dy * 5 + dx];
                }
            double D64 = 0.1 + 0.9 * sqrt(s64);
            code = D64 > 0.7 ? 2 : (D64 > 0.4 ? 1 : 0);
            Dout = (float)D64;
        } else {
            code = D32 > 0.7f ? 2 : (D32 > 0.4f ? 1 : 0);
        }
        unsigned u = (__float_as_uint(Dout) & ~3u) | (unsigned)code;
        dens[(size_t)b * Himg * Wimg + (size_t)(by + oy) * Wimg + (bx + ox)] =
            __uint_as_float(u);
    }
}

// ---------------- kernel 3: phase-separated prefetch streamer --------------
// Each thread prefetches 8 rnd float4 + 8 dens words into REGISTERS (16
// outstanding loads), then computes and stores coords f4 + weights f2.
// Chip-wide effect with the whole grid co-resident: a pure-read burst
// followed by a pure-write burst — avoids read<->write turnaround mixing
// (R11's 5-stream concurrent mix measured 3.6 TB/s; fillBuffer pure-write
// measures 7.0 TB/s). No LDS, no barriers.
__global__ __launch_bounds__(256) void stream_kernel(const float* __restrict__ rnd,
                                                     const float* __restrict__ dens,
                                                     float* __restrict__ coords,
                                                     float* __restrict__ weights) {
    int t0 = blockIdx.x * 2048 + threadIdx.x;   // item = half-pixel id; 8 per thread
    f4 r[8];
    float d[8];
    #pragma unroll
    for (int k = 0; k < 8; ++k) {
        int t = t0 + k * 256;
        r[k] = ((const f4*)rnd)[t];             // lane-contiguous 1KB/wave
        d[k] = dens[t >> 1];                    // 2-lane shared, coalesced
    }

    const float cy = (2.0f / TH) * 0.8f;
    const float cx = (2.0f / TW) * 0.8f;
    #pragma unroll
    for (int k = 0; k < 8; ++k) {
        int t = t0 + k * 256;
        int p = t >> 1;
        int h = t & 1;                          // half: slots {0,1} or {2,3}
        float local = d[k];
        int code = __float_as_uint(local) & 3;
        int num = 1 << code;
        bool useoff = num > 1;

        int rem = p & (Himg * Wimg - 1);
        float yb = -1.0f + (rem >> 9) * (2.0f / (TH - 1));
        float xb = -1.0f + (rem & 511) * (2.0f / (TW - 1));

        f4 rr = r[k];
        f4 c;
        c.x = yb + (useoff ? (rr.x - 0.5f) * cy : 0.0f);
        c.y = xb + (useoff ? (rr.y - 0.5f) * cx : 0.0f);
        c.z = yb + (useoff ? (rr.z - 0.5f) * cy : 0.0f);
        c.w = xb + (useoff ? (rr.w - 0.5f) * cx : 0.0f);
        ((f4*)coords)[t] = c;

        // local / num, num in {1,2,4}: exact pow2 scale
        float invw = local * __uint_as_float(0x3f800000u - ((unsigned)code << 23));
        f2 w;
        if (h == 0) {
            w.x = invw;
            w.y = (num > 1) ? invw : 0.0f;
        } else {
            float v = (num > 3) ? invw : 0.0f;
            w.x = v;
            w.y = v;
        }
        ((f2*)weights)[t] = w;
    }
}

extern "C" void kernel_launch(void* const* d_in, const int* in_sizes, int n_in,
                              void* d_out, int out_size, void* d_ws, size_t ws_size,
                              hipStream_t stream) {
    const float* cm   = (const float*)d_in[0];
    const float* rnd  = (const float*)d_in[1];
    const float* kern = (const float*)d_in[2];
    float* out     = (float*)d_out;
    float* coords  = out;                                   // 8*512*512*4*2
    float* weights = out + (size_t)B * TH * TW * 8;         // 8*512*512*4
    float* dens    = weights + (size_t)B * TH * TW * 4;     // 8*512*512
    float* wsmin   = (float*)d_ws;                          // 256 floats
    float* wsmax   = wsmin + B * BPB;                       // 256 floats

    minmax_kernel<<<B * BPB, 256, 0, stream>>>(cm, wsmin, wsmax);
    dim3 gridD(Wimg / 32, Himg / 32, B);
    density_kernel<<<gridD, 256, 0, stream>>>(cm, kern, wsmin, wsmax, dens);
    stream_kernel<<<2 * NPIX / 2048, 256, 0, stream>>>(rnd, dens, coords, weights);
}

// Round 13
// 55.507 us; speedup vs baseline: 1.0665x; 1.0481x over previous
//
#include <hip/hip_runtime.h>

static constexpr int B = 8, Himg = 512, Wimg = 512, TH = 512, TW = 512;
static constexpr int NPIX = B * Himg * Wimg;          // 2,097,152
static constexpr int BPB = 32;                        // minmax blocks per batch

typedef float f4 __attribute__((ext_vector_type(4)));

// ---------------- kernel 1: per-block min/max partials (no atomics) --------
__global__ __launch_bounds__(256) void minmax_kernel(const float* __restrict__ cm,
                                                     float* __restrict__ wsmin,
                                                     float* __restrict__ wsmax) {
    int b   = blockIdx.x / BPB;
    int blk = blockIdx.x % BPB;
    const f4* p = (const f4*)(cm + (size_t)b * Himg * Wimg);
    float mn = 3.4e38f, mx = -3.4e38f;
    int base = blk * 2048;
    #pragma unroll
    for (int k = 0; k < 8; ++k) {
        f4 v = p[base + k * 256 + threadIdx.x];
        mn = fminf(mn, fminf(fminf(v.x, v.y), fminf(v.z, v.w)));
        mx = fmaxf(mx, fmaxf(fmaxf(v.x, v.y), fmaxf(v.z, v.w)));
    }
    #pragma unroll
    for (int off = 32; off; off >>= 1) {
        mn = fminf(mn, __shfl_xor(mn, off));
        mx = fmaxf(mx, __shfl_xor(mx, off));
    }
    __shared__ float smn[4], smx[4];
    int wave = threadIdx.x >> 6, lane = threadIdx.x & 63;
    if (lane == 0) { smn[wave] = mn; smx[wave] = mx; }
    __syncthreads();
    if (threadIdx.x == 0) {
        mn = fminf(fminf(smn[0], smn[1]), fminf(smn[2], smn[3]));
        mx = fmaxf(fmaxf(smx[0], smx[1]), fmaxf(smx[2], smx[3]));
        wsmin[b * BPB + blk] = mn;
        wsmax[b * BPB + blk] = mx;
    }
}

// ---------------- kernel 2: density + weights (f32 conv + f64 fixup) -------
// |D_f32 - D_f64| <= ~3e-6; pixels with |D32 - thr| >= 1e-4 decide identically
// to the f64/numpy reference; rare borderline pixels recomputed exactly (f64
// 25-tap from global). Decision (num = 1<<code) encoded in the 2 low mantissa
// bits of the stored density. WEIGHTS are written here too (they depend only
// on density) so the big streaming kernel stays pure copy-shaped.
__global__ __launch_bounds__(256) void density_kernel(const float* __restrict__ cm,
                                                      const float* __restrict__ kern,
                                                      const float* __restrict__ wsmin,
                                                      const float* __restrict__ wsmax,
                                                      float* __restrict__ dens,
                                                      float* __restrict__ weights) {
    __shared__ float tile[36][37];      // normalized halo, f32 (padded stride)
    __shared__ float kf[25];

    int tid = threadIdx.x;
    int b = blockIdx.z;
    int bx = blockIdx.x * 32, by = blockIdx.y * 32;

    if (tid < 25) kf[tid] = kern[tid];

    float mnf = 3.4e38f, mxf = -3.4e38f;
    #pragma unroll
    for (int k = 0; k < BPB; ++k) {
        mnf = fminf(mnf, wsmin[b * BPB + k]);
        mxf = fmaxf(mxf, wsmax[b * BPB + k]);
    }
    bool ok = mxf > mnf;
    double mn = (double)mnf;
    double inv = ok ? (1.0 / ((double)mxf - mn)) : 0.0;
    float mnf32 = mnf;
    float invf32 = (float)inv;

    const float* img = cm + (size_t)b * Himg * Wimg;
    for (int idx = tid; idx < 36 * 36; idx += 256) {
        int r = idx / 36, c = idx % 36;
        int gy = by + r - 2, gx = bx + c - 2;
        float v = 0.0f;
        if (gy >= 0 && gy < Himg && gx >= 0 && gx < Wimg)
            v = ok ? (img[gy * Wimg + gx] - mnf32) * invf32 : 0.0f;
        tile[r][c] = v;
    }
    __syncthreads();

    int ox = tid & 31;
    int oy0 = (tid >> 5) << 2;                    // 0,4,...,28
    float acc[4] = {0.f, 0.f, 0.f, 0.f};
    #pragma unroll
    for (int yy = 0; yy < 8; ++yy) {
        float rv[5];
        #pragma unroll
        for (int dx = 0; dx < 5; ++dx) rv[dx] = tile[oy0 + yy][ox + dx];
        #pragma unroll
        for (int r = 0; r < 4; ++r) {
            int dy = yy - r;
            if (dy >= 0 && dy < 5) {
                #pragma unroll
                for (int dx = 0; dx < 5; ++dx)
                    acc[r] = fmaf(rv[dx], kf[dy * 5 + dx], acc[r]);
            }
        }
    }
    #pragma unroll
    for (int r = 0; r < 4; ++r) {
        int oy = oy0 + r;
        float D32 = 0.1f + 0.9f * sqrtf(fmaxf(acc[r], 0.0f));
        float Dout = D32;
        int code;
        if (fabsf(D32 - 0.7f) < 1e-4f || fabsf(D32 - 0.4f) < 1e-4f) {
            double s64 = 0.0;
            #pragma unroll
            for (int dy = 0; dy < 5; ++dy)
                for (int dx = 0; dx < 5; ++dx) {
                    int gy = by + oy + dy - 2, gx = bx + ox + dx - 2;
                    double v = 0.0;
                    if (gy >= 0 && gy < Himg && gx >= 0 && gx < Wimg)
                        v = ((double)img[gy * Wimg + gx] - mn) * inv;
                    s64 += v * (double)kern[dy * 5 + dx];
                }
            double D64 = 0.1 + 0.9 * sqrt(s64);
            code = D64 > 0.7 ? 2 : (D64 > 0.4 ? 1 : 0);
            Dout = (float)D64;
        } else {
            code = D32 > 0.7f ? 2 : (D32 > 0.4f ? 1 : 0);
        }
        unsigned u = (__float_as_uint(Dout) & ~3u) | (unsigned)code;
        float enc = __uint_as_float(u);
        size_t pix = (size_t)b * Himg * Wimg + (size_t)(by + oy) * Wimg + (bx + ox);
        dens[pix] = enc;

        int num = 1 << code;
        // enc / num, num in {1,2,4}: exact pow2 scale
        float invw = enc * __uint_as_float(0x3f800000u - ((unsigned)code << 23));
        f4 w;
        w.x = invw;
        w.y = (num > 1) ? invw : 0.0f;
        w.z = (num > 3) ? invw : 0.0f;
        w.w = w.z;
        ((f4*)weights)[pix] = w;                  // 512B contiguous per wave-row
    }
}

// ---------------- kernel 3: copy-shaped coords streamer --------------------
// Thread = half-pixel: rnd f4 load -> trivial VALU -> coords f4 store, plus
// an L3-hot dens word shared by lane pairs. This is within epsilon of the
// measured 6.3 TB/s float4-copy shape (m13).
__global__ __launch_bounds__(256) void coords_kernel(const float* __restrict__ rnd,
                                                     const float* __restrict__ dens,
                                                     float* __restrict__ coords) {
    int t = blockIdx.x * 256 + threadIdx.x;     // half-pixel id
    int p = t >> 1;
    float local = dens[p];                      // 2 lanes/word, coalesced, L3-hot
    bool useoff = (__float_as_uint(local) & 3) != 0;

    int rem = p & (Himg * Wimg - 1);
    float yb = -1.0f + (rem >> 9) * (2.0f / (TH - 1));
    float xb = -1.0f + (rem & 511) * (2.0f / (TW - 1));
    const float cy = (2.0f / TH) * 0.8f;
    const float cx = (2.0f / TW) * 0.8f;

    f4 r = ((const f4*)rnd)[t];
    f4 c;
    c.x = yb + (useoff ? (r.x - 0.5f) * cy : 0.0f);
    c.y = xb + (useoff ? (r.y - 0.5f) * cx : 0.0f);
    c.z = yb + (useoff ? (r.z - 0.5f) * cy : 0.0f);
    c.w = xb + (useoff ? (r.w - 0.5f) * cx : 0.0f);
    ((f4*)coords)[t] = c;
}

extern "C" void kernel_launch(void* const* d_in, const int* in_sizes, int n_in,
                              void* d_out, int out_size, void* d_ws, size_t ws_size,
                              hipStream_t stream) {
    const float* cm   = (const float*)d_in[0];
    const float* rnd  = (const float*)d_in[1];
    const float* kern = (const float*)d_in[2];
    float* out     = (float*)d_out;
    float* coords  = out;                                   // 8*512*512*4*2
    float* weights = out + (size_t)B * TH * TW * 8;         // 8*512*512*4
    float* dens    = weights + (size_t)B * TH * TW * 4;     // 8*512*512
    float* wsmin   = (float*)d_ws;                          // 256 floats
    float* wsmax   = wsmin + B * BPB;                       // 256 floats

    minmax_kernel<<<B * BPB, 256, 0, stream>>>(cm, wsmin, wsmax);
    dim3 gridD(Wimg / 32, Himg / 32, B);
    density_kernel<<<gridD, 256, 0, stream>>>(cm, kern, wsmin, wsmax, dens, weights);
    coords_kernel<<<2 * NPIX / 256, 256, 0, stream>>>(rnd, dens, coords);
}

// Round 14
// 47.458 us; speedup vs baseline: 1.2473x; 1.1696x over previous
//
#include <hip/hip_runtime.h>

static constexpr int B = 8, Himg = 512, Wimg = 512, TH = 512, TW = 512;
static constexpr int BPB = 32;                        // minmax blocks per batch

typedef float f4 __attribute__((ext_vector_type(4)));
typedef float f2 __attribute__((ext_vector_type(2)));

// ---------------- kernel 1: per-block min/max partials (no atomics) --------
__global__ __launch_bounds__(256) void minmax_kernel(const float* __restrict__ cm,
                                                     float* __restrict__ wsmin,
                                                     float* __restrict__ wsmax) {
    int b   = blockIdx.x / BPB;
    int blk = blockIdx.x % BPB;
    const f4* p = (const f4*)(cm + (size_t)b * Himg * Wimg);
    float mn = 3.4e38f, mx = -3.4e38f;
    int base = blk * 2048;
    #pragma unroll
    for (int k = 0; k < 8; ++k) {
        f4 v = p[base + k * 256 + threadIdx.x];
        mn = fminf(mn, fminf(fminf(v.x, v.y), fminf(v.z, v.w)));
        mx = fmaxf(mx, fmaxf(fmaxf(v.x, v.y), fmaxf(v.z, v.w)));
    }
    #pragma unroll
    for (int off = 32; off; off >>= 1) {
        mn = fminf(mn, __shfl_xor(mn, off));
        mx = fmaxf(mx, __shfl_xor(mx, off));
    }
    __shared__ float smn[4], smx[4];
    int wave = threadIdx.x >> 6, lane = threadIdx.x & 63;
    if (lane == 0) { smn[wave] = mn; smx[wave] = mx; }
    __syncthreads();
    if (threadIdx.x == 0) {
        mn = fminf(fminf(smn[0], smn[1]), fminf(smn[2], smn[3]));
        mx = fmaxf(fmaxf(smx[0], smx[1]), fmaxf(smx[2], smx[3]));
        wsmin[b * BPB + blk] = mn;
        wsmax[b * BPB + blk] = mx;
    }
}

// ---------------- kernel 2: fused density + sampler ------------------------
// Per 32x32 tile: f64 normalize + EXACT 25-tap f64 conv with the f32 kernel
// entries (separable factorization is WRONG: k2 entries are individually
// f32-rounded, so k1'(x)k1' differs by ~6e-8 -> threshold flips) -> density
// + 0.4/0.7 decision encoded in 2 low mantissa bits -> LDS + global ->
// stream-sample the tile with lane-contiguous half-pixel accesses.
__global__ __launch_bounds__(256) void fused_kernel(const float* __restrict__ cm,
                                                    const float* __restrict__ kern,
                                                    const float* __restrict__ wsmin,
                                                    const float* __restrict__ wsmax,
                                                    const float* __restrict__ rnd,
                                                    float* __restrict__ coords,
                                                    float* __restrict__ weights,
                                                    float* __restrict__ dens) {
    __shared__ double tile[36][37];     // normalized halo (padded stride)
    __shared__ double kd[25];
    __shared__ float dsm[1024];         // encoded density for phase 3

    int tid = threadIdx.x;
    int b = blockIdx.z;
    int bx = blockIdx.x * 32, by = blockIdx.y * 32;

    if (tid < 25) kd[tid] = (double)kern[tid];

    float mnf = 3.4e38f, mxf = -3.4e38f;
    #pragma unroll
    for (int k = 0; k < BPB; ++k) {
        mnf = fminf(mnf, wsmin[b * BPB + k]);
        mxf = fmaxf(mxf, wsmax[b * BPB + k]);
    }
    bool ok = mxf > mnf;
    double mn = (double)mnf;
    double inv = ok ? (1.0 / ((double)mxf - mn)) : 0.0;   // recip-mul: ≤1ulp vs div

    // phase 1: normalized halo (zero padding outside image)
    const float* img = cm + (size_t)b * Himg * Wimg;
    for (int idx = tid; idx < 36 * 36; idx += 256) {
        int r = idx / 36, c = idx % 36;
        int gy = by + r - 2, gx = bx + c - 2;
        double v = 0.0;
        if (gy >= 0 && gy < Himg && gx >= 0 && gx < Wimg)
            v = ((double)img[gy * Wimg + gx] - mn) * inv;
        tile[r][c] = v;
    }
    __syncthreads();

    // phase 2: exact 25-tap f64 conv + density + decision -> LDS + global
    for (int p = tid; p < 32 * 32; p += 256) {
        int oy = p >> 5, ox = p & 31;
        double s = 0.0;
        #pragma unroll
        for (int dy = 0; dy < 5; ++dy)
            #pragma unroll
            for (int dx = 0; dx < 5; ++dx)
                s += tile[oy + dy][ox + dx] * kd[dy * 5 + dx];
        double D = 0.1 + 0.9 * sqrt(s);
        int code = D > 0.7 ? 2 : (D > 0.4 ? 1 : 0);   // num = 1<<code
        unsigned u = (__float_as_uint((float)D) & ~3u) | (unsigned)code;
        float enc = __uint_as_float(u);
        dsm[p] = enc;
        dens[(size_t)b * Himg * Wimg + (size_t)(by + oy) * Wimg + (bx + ox)] = enc;
    }
    __syncthreads();

    // phase 3: streaming sampler, one row of 64 half-pixels per wave-iter
    const float cy = (2.0f / TH) * 0.8f;
    const float cx = (2.0f / TW) * 0.8f;
    int lane = tid & 63, wv = tid >> 6;
    #pragma unroll
    for (int k = 0; k < 8; ++k) {
        int row = k * 4 + wv;                         // 0..31
        int gy = by + row;
        int gx = bx + (lane >> 1);
        int h = lane & 1;                             // half: slots {0,1} or {2,3}

        float local = dsm[row * 32 + (lane >> 1)];    // paired-lane broadcast
        int code = __float_as_uint(local) & 3;
        int num = 1 << code;
        bool useoff = num > 1;

        float yb = -1.0f + gy * (2.0f / (TH - 1));
        float xb = -1.0f + gx * (2.0f / (TW - 1));

        size_t f4i = 2 * ((size_t)b * (Himg * Wimg) + (size_t)gy * Wimg + bx) + lane;
        f4 r = ((const f4*)rnd)[f4i];                 // 1KB contiguous per wave
        f4 c;
        c.x = yb + (useoff ? (r.x - 0.5f) * cy : 0.0f);
        c.y = xb + (useoff ? (r.y - 0.5f) * cx : 0.0f);
        c.z = yb + (useoff ? (r.z - 0.5f) * cy : 0.0f);
        c.w = xb + (useoff ? (r.w - 0.5f) * cx : 0.0f);
        ((f4*)coords)[f4i] = c;

        // local / num, num in {1,2,4}: exact pow2 scale
        float invw = local * __uint_as_float(0x3f800000u - ((unsigned)code << 23));
        f2 w;
        if (h == 0) {
            w.x = invw;
            w.y = (num > 1) ? invw : 0.0f;
        } else {
            float v = (num > 3) ? invw : 0.0f;
            w.x = v;
            w.y = v;
        }
        ((f2*)weights)[f4i] = w;                      // 512B contiguous per wave
    }
}

extern "C" void kernel_launch(void* const* d_in, const int* in_sizes, int n_in,
                              void* d_out, int out_size, void* d_ws, size_t ws_size,
                              hipStream_t stream) {
    const float* cm   = (const float*)d_in[0];
    const float* rnd  = (const float*)d_in[1];
    const float* kern = (const float*)d_in[2];
    float* out     = (float*)d_out;
    float* coords  = out;                                   // 8*512*512*4*2
    float* weights = out + (size_t)B * TH * TW * 8;         // 8*512*512*4
    float* dens    = weights + (size_t)B * TH * TW * 4;     // 8*512*512
    float* wsmin   = (float*)d_ws;                          // 256 floats
    float* wsmax   = wsmin + B * BPB;                       // 256 floats

    minmax_kernel<<<B * BPB, 256, 0, stream>>>(cm, wsmin, wsmax);
    dim3 gridF(Wimg / 32, Himg / 32, B);
    fused_kernel<<<gridF, 256, 0, stream>>>(cm, kern, wsmin, wsmax, rnd,
                                            coords, weights, dens);
}